// Round 3
// baseline (756.768 us; speedup 1.0000x reference)
//
#include <hip/hip_runtime.h>

namespace {

constexpr int NFFT  = 65536;   // complex FFT length (half of 131072)
constexpr int KEEPK = 32768;   // rfft bins 0..32768 kept (keep = 32769)
constexpr int OUTW  = 65409;   // W - K + 1
constexpr size_t YBYTES = (size_t)128 * 32769 * 8;  // full weight rfft spectrum

typedef float2 cplx;

__device__ __forceinline__ cplx cmk(float x, float y){ return make_float2(x, y); }
__device__ __forceinline__ cplx cadd(cplx a, cplx b){ return cmk(a.x+b.x, a.y+b.y); }
__device__ __forceinline__ cplx csub(cplx a, cplx b){ return cmk(a.x-b.x, a.y-b.y); }
__device__ __forceinline__ cplx cmul(cplx a, cplx b){ return cmk(a.x*b.x - a.y*b.y, a.x*b.y + a.y*b.x); }
__device__ __forceinline__ cplx cmulj(cplx a, cplx b){ // a * conj(b)
  return cmk(a.x*b.x + a.y*b.y, a.y*b.x - a.x*b.y); }

// 16-point complex DFT, natural order in/out. DIR=-1 forward (e^{-i}), +1 inverse (unnormalized).
template<int DIR>
__device__ __forceinline__ void dft16(cplx v[16]) {
  const float C1 = 0.92387953251128674f;
  const float S1 = 0.38268343236508977f;
  const float C2 = 0.70710678118654752f;
  const float WR[16]  = {1.f, C1, C2, S1, 0.f, -S1, -C2, -C1, -1.f, -C1, -C2, -S1, 0.f, S1, C2, C1};
  const float WIF[16] = {0.f, -S1, -C2, -C1, -1.f, -C1, -C2, -S1, 0.f, S1, C2, C1, 1.f, C1, C2, S1};
  cplx s[16];
  #pragma unroll
  for (int n2 = 0; n2 < 4; ++n2) {
    cplx a = v[n2], b = v[n2+4], c = v[n2+8], d = v[n2+12];
    cplx ac = cadd(a,c), am = csub(a,c), bd = cadd(b,d), bm = csub(b,d);
    cplx x0 = cadd(ac, bd), x2 = csub(ac, bd), x1, x3;
    if (DIR == -1) { x1 = cmk(am.x + bm.y, am.y - bm.x); x3 = cmk(am.x - bm.y, am.y + bm.x); }
    else           { x1 = cmk(am.x - bm.y, am.y + bm.x); x3 = cmk(am.x + bm.y, am.y - bm.x); }
    s[0*4+n2] = x0;
    {
      int e1 = (n2*1) & 15, e2 = (n2*2) & 15, e3 = (n2*3) & 15;
      cplx w1 = cmk(WR[e1], (DIR==-1)? WIF[e1] : -WIF[e1]);
      cplx w2 = cmk(WR[e2], (DIR==-1)? WIF[e2] : -WIF[e2]);
      cplx w3 = cmk(WR[e3], (DIR==-1)? WIF[e3] : -WIF[e3]);
      s[1*4+n2] = cmul(x1, w1);
      s[2*4+n2] = cmul(x2, w2);
      s[3*4+n2] = cmul(x3, w3);
    }
  }
  #pragma unroll
  for (int t1 = 0; t1 < 4; ++t1) {
    cplx a = s[t1*4+0], b = s[t1*4+1], c = s[t1*4+2], d = s[t1*4+3];
    cplx ac = cadd(a,c), am = csub(a,c), bd = cadd(b,d), bm = csub(b,d);
    cplx x0 = cadd(ac,bd), x2 = csub(ac,bd), x1, x3;
    if (DIR == -1) { x1 = cmk(am.x + bm.y, am.y - bm.x); x3 = cmk(am.x - bm.y, am.y + bm.x); }
    else           { x1 = cmk(am.x - bm.y, am.y + bm.x); x3 = cmk(am.x + bm.y, am.y - bm.x); }
    v[t1+0] = x0; v[t1+4] = x1; v[t1+8] = x2; v[t1+12] = x3;
  }
}

// Four-step pass A: inner 256-pt DFTs over a (z[a*256+b]) + big twiddle via recurrence.
// Output T[seq][b][k1] (b-major). Input zero-padded past inLen.
template<int DIR>
__global__ __launch_bounds__(256)
void fft_pass_a(const cplx* __restrict__ in, long inStride, int inLen,
                cplx* __restrict__ T) {
  int blk = blockIdx.x;
  int seq = blk >> 4;
  int B0  = (blk & 15) << 4;
  int t = threadIdx.x;
  __shared__ cplx tile[16][260];
  {
    const cplx* src = in + (long)seq * inStride;
    int cb = t & 15, rg = t >> 4;
    #pragma unroll
    for (int i = 0; i < 16; ++i) {
      int a = i*16 + rg;
      int sIdx = a*256 + B0 + cb;
      cplx v = (sIdx < inLen) ? src[sIdx] : cmk(0.f, 0.f);
      tile[cb][a] = v;
    }
  }
  __syncthreads();
  int cc = t >> 4, j = t & 15;
  cplx x[16];
  #pragma unroll
  for (int a1 = 0; a1 < 16; ++a1) x[a1] = tile[cc][a1*16 + j];
  dft16<DIR>(x);
  {
    // x[t1] *= w256^(j*t1) via rotation recurrence (1 sincos)
    float sn, cs;
    __sincosf((float)DIR * 6.28318530717958648f * (float)j * (1.0f/256.0f), &sn, &cs);
    cplx r = cmk(cs, sn), cur = r;
    #pragma unroll
    for (int t1 = 1; t1 < 16; ++t1) { x[t1] = cmul(x[t1], cur); cur = cmul(cur, r); }
  }
  __syncthreads();
  #pragma unroll
  for (int t1 = 0; t1 < 16; ++t1) tile[cc][t1*16 + ((j + t1) & 15)] = x[t1];
  __syncthreads();
  #pragma unroll
  for (int a2 = 0; a2 < 16; ++a2) x[a2] = tile[cc][j*16 + ((a2 + j) & 15)];
  dft16<DIR>(x);
  int b = B0 + cc;
  cplx* dst = T + (long)seq * NFFT + (long)b * 256;
  {
    // dst[j+16*t2] = x[t2] * W65536^(b*(j+16*t2)) via recurrence (2 sincos)
    float sn, cs;
    __sincosf((float)DIR * 6.28318530717958648f * (float)(b*j) * (1.0f/65536.0f), &sn, &cs);
    cplx cur = cmk(cs, sn);
    __sincosf((float)DIR * 6.28318530717958648f * (float)b * (1.0f/4096.0f), &sn, &cs);
    cplx stp = cmk(cs, sn);
    #pragma unroll
    for (int t2 = 0; t2 < 16; ++t2) {
      dst[j + 16*t2] = cmul(x[t2], cur);
      cur = cmul(cur, stp);
    }
  }
}

// Four-step pass B: outer 256-pt DFTs over b for each k1.
// MODE 0: store Z[seq][k1+256*k2]. MODE 1: inverse-final — out[seqBase+seq][2s(,+1)]
// = (Re,Im)/65536 + bias[(seqBase+seq)&15], truncated at OUTW.
template<int DIR, int MODE>
__global__ __launch_bounds__(256)
void fft_pass_b(const cplx* __restrict__ T, cplx* __restrict__ outZ,
                float* __restrict__ outR, const float* __restrict__ bias,
                int seqBase) {
  int blk = blockIdx.x;
  int seq = blk >> 4;
  int K0  = (blk & 15) << 4;
  int t = threadIdx.x;
  __shared__ cplx tile[16][260];
  {
    const cplx* src = T + (long)seq * NFFT;
    int ck = t & 15, rg = t >> 4;
    #pragma unroll
    for (int i = 0; i < 16; ++i) {
      int b = i*16 + rg;
      tile[ck][b] = src[b*256 + K0 + ck];
    }
  }
  __syncthreads();
  int cc = t >> 4, j = t & 15;
  cplx x[16];
  #pragma unroll
  for (int a1 = 0; a1 < 16; ++a1) x[a1] = tile[cc][a1*16 + j];
  dft16<DIR>(x);
  {
    float sn, cs;
    __sincosf((float)DIR * 6.28318530717958648f * (float)j * (1.0f/256.0f), &sn, &cs);
    cplx r = cmk(cs, sn), cur = r;
    #pragma unroll
    for (int t1 = 1; t1 < 16; ++t1) { x[t1] = cmul(x[t1], cur); cur = cmul(cur, r); }
  }
  __syncthreads();
  #pragma unroll
  for (int t1 = 0; t1 < 16; ++t1) tile[cc][t1*16 + ((j + t1) & 15)] = x[t1];
  __syncthreads();
  #pragma unroll
  for (int a2 = 0; a2 < 16; ++a2) x[a2] = tile[cc][j*16 + ((a2 + j) & 15)];
  dft16<DIR>(x);
  __syncthreads();  // before reusing tile as staging
  #pragma unroll
  for (int t2 = 0; t2 < 16; ++t2) tile[cc][j + 16*t2] = x[t2];
  __syncthreads();
  int ck2 = t & 15, rg2 = t >> 4;
  if (MODE == 0) {
    cplx* dst = outZ + (long)seq * NFFT + K0 + ck2;
    #pragma unroll
    for (int i = 0; i < 16; ++i) {
      int k2 = i*16 + rg2;
      dst[256*k2] = tile[ck2][k2];
    }
  } else {
    const float sc = 1.0f / 65536.0f;
    int gseq = seqBase + seq;
    float bf = bias[gseq & 15];
    float* dst = outR + (long)gseq * OUTW;
    #pragma unroll
    for (int i = 0; i < 16; ++i) {
      int k2 = i*16 + rg2;
      int s  = K0 + ck2 + 256*k2;
      int tp = 2*s;
      cplx v = tile[ck2][k2];
      if (tp < OUTW)     dst[tp]   = v.x * sc + bf;
      if (tp + 1 < OUTW) dst[tp+1] = v.y * sc + bf;
    }
  }
}

// Direct weight rfft: Y[seq][k] = sum_{t<128} w[seq][t] e^{-2 pi i k t / 131072},
// k = 0..32768. 4-way-unrolled rotation recurrence, taps staged in LDS.
__global__ __launch_bounds__(256)
void weight_spec(const float* __restrict__ wgt, cplx* __restrict__ Y) {
  int seq = blockIdx.y;
  int k = blockIdx.x * 256 + threadIdx.x;
  __shared__ float wt[128];
  if (threadIdx.x < 128) wt[threadIdx.x] = wgt[seq * 128 + threadIdx.x];
  __syncthreads();
  if (k > KEEPK) return;
  float sn, cs;
  __sincosf(-3.14159265358979324f * (float)k * (1.0f/65536.0f), &sn, &cs);
  cplx r  = cmk(cs, sn);
  cplx r2 = cmul(r, r);
  cplx r4 = cmul(r2, r2);
  cplx c0 = cmk(1.f, 0.f);
  cplx acc = cmk(0.f, 0.f);
  #pragma unroll 8
  for (int t = 0; t < 128; t += 4) {
    cplx c1 = cmul(c0, r);
    cplx c2 = cmul(c0, r2);
    cplx c3 = cmul(c1, r2);
    acc.x += wt[t]*c0.x + wt[t+1]*c1.x + wt[t+2]*c2.x + wt[t+3]*c3.x;
    acc.y += wt[t]*c0.y + wt[t+1]*c1.y + wt[t+2]*c2.y + wt[t+3]*c3.y;
    c0 = cmul(c0, r4);
  }
  Y[(long)seq * 32769 + k] = acc;
}

// Fused: unpack X on the fly, 8-channel complex MAC vs conj(Y) for all 16 f,
// Hermitian-pack the masked product spectrum into inverse-FFT input Z.
__global__ __launch_bounds__(256)
void mac_pack(const cplx* __restrict__ Zx, const cplx* __restrict__ Yspec,
              cplx* __restrict__ Zout, int Bn) {
  int K0 = blockIdx.x * 64;
  int tid = threadIdx.x;
  int kk = tid & 63;
  int ng = tid >> 6;       // 4 thread-groups over n
  int k = K0 + kk;
  __shared__ cplx Yt[16][8][64];  // 64 KiB
  for (int e = tid; e < 16*8*64; e += 256) {
    int f = e >> 9;
    int c = (e >> 6) & 7;
    int q = e & 63;
    int kg = K0 + q;
    Yt[f][c][q] = (kg <= KEEPK) ? Yspec[(long)(f*8 + c) * 32769 + kg] : cmk(0.f, 0.f);
  }
  __syncthreads();
  if (k > KEEPK) return;
  float sn, cs;
  __sincosf(-3.14159265358979324f * (float)k * (1.0f/65536.0f), &sn, &cs);
  cplx w  = cmk(cs, sn);    // e^{-i pi k / 65536}
  cplx wp = cmk(cs, -sn);   // conj(w)
  int nPerG = (Bn + 3) >> 2;
  for (int nn = 0; nn < nPerG; ++nn) {
    int ln = ng * nPerG + nn;
    if (ln >= Bn) break;
    cplx X[8];
    #pragma unroll
    for (int c = 0; c < 8; ++c) {
      const cplx* Z = Zx + (long)(ln*8 + c) * NFFT;
      cplx zk = Z[k];
      cplx zm = Z[(NFFT - k) & (NFFT - 1)];
      cplx E = cmk(0.5f*(zk.x + zm.x), 0.5f*(zk.y - zm.y));
      cplx D = cmk(zk.x - zm.x, zk.y + zm.y);
      cplx O = cmk(0.5f*D.y, -0.5f*D.x);
      X[c] = cadd(E, cmul(w, O));
    }
    #pragma unroll
    for (int f = 0; f < 16; ++f) {
      cplx S = cmk(0.f, 0.f);
      #pragma unroll
      for (int c = 0; c < 8; ++c) S = cadd(S, cmulj(X[c], Yt[f][c][kk]));
      cplx* Zo = Zout + (long)(ln*16 + f) * NFFT;
      if (k == KEEPK) {
        Zo[k] = cmk(S.x, -S.y);                  // Z[M/2] = conj(S)
      } else {
        cplx E2 = cmk(0.5f*S.x, 0.5f*S.y);
        cplx O2 = cmul(wp, E2);                  // e^{+i pi k/M} * S/2
        Zo[k] = cmk(E2.x - O2.y, E2.y + O2.x);   // E + i O
        if (k > 0)
          Zo[NFFT - k] = cmk(E2.x + O2.y, O2.x - E2.y); // conj(E) + i conj(O)
      }
    }
  }
}

} // namespace

extern "C" void kernel_launch(void* const* d_in, const int* in_sizes, int n_in,
                              void* d_out, int out_size, void* d_ws, size_t ws_size,
                              hipStream_t stream) {
  const cplx*  x    = (const cplx*)d_in[0];   // (32,8,65536) f32 = 32768 cplx/seq, 256 seqs
  const float* wgt  = (const float*)d_in[1];  // (16,8,128)  f32, 128 seqs of 128 taps
  const float* bias = (const float*)d_in[2];  // (16,)
  float* out = (float*)d_out;                 // (32,16,65409) f32

  // Region plan: Y (33.6 MB) + Zx (Bn*8 seqs) + Zout (Bn*16) + T (Bn*16), batched over n.
  static const int BnOpt[5] = {16, 8, 4, 2, 1};
  int ti = 4;
  for (int i = 0; i < 5; ++i) {
    size_t zxb = (size_t)BnOpt[i] * 8  * NFFT * sizeof(cplx);
    size_t zob = (size_t)BnOpt[i] * 16 * NFFT * sizeof(cplx);
    if (YBYTES + zxb + 2 * zob <= ws_size) { ti = i; break; }
  }
  const int Bn = BnOpt[ti];
  const size_t zxb = (size_t)Bn * 8  * NFFT * sizeof(cplx);
  const size_t zob = (size_t)Bn * 16 * NFFT * sizeof(cplx);

  char* ws = (char*)d_ws;
  cplx* Y  = (cplx*)ws;                         // weight rfft spectrum, whole pipeline
  cplx* Zx = (cplx*)(ws + YBYTES);              // per-batch x spectra
  cplx* Zo = (cplx*)(ws + YBYTES + zxb);        // per-batch product spectra
  cplx* T  = (cplx*)(ws + YBYTES + zxb + zob);  // shared four-step temp

  // weight spectrum: one direct-DFT kernel
  weight_spec<<<dim3(129, 128), dim3(256), 0, stream>>>(wgt, Y);

  // per n-batch: x FFT -> MAC -> inverse FFT
  for (int n0 = 0; n0 < 32; n0 += Bn) {
    int sx = Bn * 8;   // x seqs this batch
    int so = Bn * 16;  // out seqs this batch
    fft_pass_a<-1><<<dim3(sx*16), dim3(256), 0, stream>>>(x + (long)n0*8*32768, 32768, 32768, T);
    fft_pass_b<-1,0><<<dim3(sx*16), dim3(256), 0, stream>>>(T, Zx, (float*)nullptr, (const float*)nullptr, 0);
    mac_pack<<<dim3(513), dim3(256), 0, stream>>>(Zx, Y, Zo, Bn);
    fft_pass_a<1><<<dim3(so*16), dim3(256), 0, stream>>>(Zo, 65536, 65536, T);
    fft_pass_b<1,1><<<dim3(so*16), dim3(256), 0, stream>>>(T, (cplx*)nullptr, out, bias, n0*16);
  }
}

// Round 4
// 662.894 us; speedup vs baseline: 1.1416x; 1.1416x over previous
//
#include <hip/hip_runtime.h>

namespace {

constexpr int NFFT  = 65536;   // complex FFT length (half of 131072)
constexpr int KEEPK = 32768;   // rfft bins 0..32768 kept (keep = 32769)
constexpr int OUTW  = 65409;   // W - K + 1
constexpr size_t YBYTES = (size_t)128 * 32769 * 8;  // full weight rfft spectrum

typedef float2 cplx;

__device__ __forceinline__ cplx cmk(float x, float y){ return make_float2(x, y); }
__device__ __forceinline__ cplx cadd(cplx a, cplx b){ return cmk(a.x+b.x, a.y+b.y); }
__device__ __forceinline__ cplx csub(cplx a, cplx b){ return cmk(a.x-b.x, a.y-b.y); }
__device__ __forceinline__ cplx cmul(cplx a, cplx b){ return cmk(a.x*b.x - a.y*b.y, a.x*b.y + a.y*b.x); }
__device__ __forceinline__ cplx cmulj(cplx a, cplx b){ // a * conj(b)
  return cmk(a.x*b.x + a.y*b.y, a.y*b.x - a.x*b.y); }

// 16-point complex DFT, natural order in/out. DIR=-1 forward (e^{-i}), +1 inverse (unnormalized).
template<int DIR>
__device__ __forceinline__ void dft16(cplx v[16]) {
  const float C1 = 0.92387953251128674f;
  const float S1 = 0.38268343236508977f;
  const float C2 = 0.70710678118654752f;
  const float WR[16]  = {1.f, C1, C2, S1, 0.f, -S1, -C2, -C1, -1.f, -C1, -C2, -S1, 0.f, S1, C2, C1};
  const float WIF[16] = {0.f, -S1, -C2, -C1, -1.f, -C1, -C2, -S1, 0.f, S1, C2, C1, 1.f, C1, C2, S1};
  cplx s[16];
  #pragma unroll
  for (int n2 = 0; n2 < 4; ++n2) {
    cplx a = v[n2], b = v[n2+4], c = v[n2+8], d = v[n2+12];
    cplx ac = cadd(a,c), am = csub(a,c), bd = cadd(b,d), bm = csub(b,d);
    cplx x0 = cadd(ac, bd), x2 = csub(ac, bd), x1, x3;
    if (DIR == -1) { x1 = cmk(am.x + bm.y, am.y - bm.x); x3 = cmk(am.x - bm.y, am.y + bm.x); }
    else           { x1 = cmk(am.x - bm.y, am.y + bm.x); x3 = cmk(am.x + bm.y, am.y - bm.x); }
    s[0*4+n2] = x0;
    {
      int e1 = (n2*1) & 15, e2 = (n2*2) & 15, e3 = (n2*3) & 15;
      cplx w1 = cmk(WR[e1], (DIR==-1)? WIF[e1] : -WIF[e1]);
      cplx w2 = cmk(WR[e2], (DIR==-1)? WIF[e2] : -WIF[e2]);
      cplx w3 = cmk(WR[e3], (DIR==-1)? WIF[e3] : -WIF[e3]);
      s[1*4+n2] = cmul(x1, w1);
      s[2*4+n2] = cmul(x2, w2);
      s[3*4+n2] = cmul(x3, w3);
    }
  }
  #pragma unroll
  for (int t1 = 0; t1 < 4; ++t1) {
    cplx a = s[t1*4+0], b = s[t1*4+1], c = s[t1*4+2], d = s[t1*4+3];
    cplx ac = cadd(a,c), am = csub(a,c), bd = cadd(b,d), bm = csub(b,d);
    cplx x0 = cadd(ac,bd), x2 = csub(ac,bd), x1, x3;
    if (DIR == -1) { x1 = cmk(am.x + bm.y, am.y - bm.x); x3 = cmk(am.x - bm.y, am.y + bm.x); }
    else           { x1 = cmk(am.x - bm.y, am.y + bm.x); x3 = cmk(am.x + bm.y, am.y - bm.x); }
    v[t1+0] = x0; v[t1+4] = x1; v[t1+8] = x2; v[t1+12] = x3;
  }
}

// Four-step pass A: inner 256-pt DFTs over a (z[a*256+b]) + big twiddle via recurrence.
// Output T[seq][b][k1] (b-major). Input zero-padded past inLen.
template<int DIR>
__global__ __launch_bounds__(256)
void fft_pass_a(const cplx* __restrict__ in, long inStride, int inLen,
                cplx* __restrict__ T) {
  int blk = blockIdx.x;
  int seq = blk >> 4;
  int B0  = (blk & 15) << 4;
  int t = threadIdx.x;
  __shared__ cplx tile[16][260];
  {
    const cplx* src = in + (long)seq * inStride;
    int cb = t & 15, rg = t >> 4;
    #pragma unroll
    for (int i = 0; i < 16; ++i) {
      int a = i*16 + rg;
      int sIdx = a*256 + B0 + cb;
      cplx v = (sIdx < inLen) ? src[sIdx] : cmk(0.f, 0.f);
      tile[cb][a] = v;
    }
  }
  __syncthreads();
  int cc = t >> 4, j = t & 15;
  cplx x[16];
  #pragma unroll
  for (int a1 = 0; a1 < 16; ++a1) x[a1] = tile[cc][a1*16 + j];
  dft16<DIR>(x);
  {
    // x[t1] *= w256^(j*t1) via rotation recurrence (1 sincos)
    float sn, cs;
    __sincosf((float)DIR * 6.28318530717958648f * (float)j * (1.0f/256.0f), &sn, &cs);
    cplx r = cmk(cs, sn), cur = r;
    #pragma unroll
    for (int t1 = 1; t1 < 16; ++t1) { x[t1] = cmul(x[t1], cur); cur = cmul(cur, r); }
  }
  __syncthreads();
  #pragma unroll
  for (int t1 = 0; t1 < 16; ++t1) tile[cc][t1*16 + ((j + t1) & 15)] = x[t1];
  __syncthreads();
  #pragma unroll
  for (int a2 = 0; a2 < 16; ++a2) x[a2] = tile[cc][j*16 + ((a2 + j) & 15)];
  dft16<DIR>(x);
  int b = B0 + cc;
  cplx* dst = T + (long)seq * NFFT + (long)b * 256;
  {
    // dst[j+16*t2] = x[t2] * W65536^(b*(j+16*t2)) via recurrence (2 sincos)
    float sn, cs;
    __sincosf((float)DIR * 6.28318530717958648f * (float)(b*j) * (1.0f/65536.0f), &sn, &cs);
    cplx cur = cmk(cs, sn);
    __sincosf((float)DIR * 6.28318530717958648f * (float)b * (1.0f/4096.0f), &sn, &cs);
    cplx stp = cmk(cs, sn);
    #pragma unroll
    for (int t2 = 0; t2 < 16; ++t2) {
      dst[j + 16*t2] = cmul(x[t2], cur);
      cur = cmul(cur, stp);
    }
  }
}

// Four-step pass B: outer 256-pt DFTs over b for each k1.
// MODE 0: store Z[seq][k1+256*k2]. MODE 1: inverse-final — out[seqBase+seq][2s(,+1)]
// = (Re,Im)/65536 + bias[(seqBase+seq)&15], truncated at OUTW.
template<int DIR, int MODE>
__global__ __launch_bounds__(256)
void fft_pass_b(const cplx* __restrict__ T, cplx* __restrict__ outZ,
                float* __restrict__ outR, const float* __restrict__ bias,
                int seqBase) {
  int blk = blockIdx.x;
  int seq = blk >> 4;
  int K0  = (blk & 15) << 4;
  int t = threadIdx.x;
  __shared__ cplx tile[16][260];
  {
    const cplx* src = T + (long)seq * NFFT;
    int ck = t & 15, rg = t >> 4;
    #pragma unroll
    for (int i = 0; i < 16; ++i) {
      int b = i*16 + rg;
      tile[ck][b] = src[b*256 + K0 + ck];
    }
  }
  __syncthreads();
  int cc = t >> 4, j = t & 15;
  cplx x[16];
  #pragma unroll
  for (int a1 = 0; a1 < 16; ++a1) x[a1] = tile[cc][a1*16 + j];
  dft16<DIR>(x);
  {
    float sn, cs;
    __sincosf((float)DIR * 6.28318530717958648f * (float)j * (1.0f/256.0f), &sn, &cs);
    cplx r = cmk(cs, sn), cur = r;
    #pragma unroll
    for (int t1 = 1; t1 < 16; ++t1) { x[t1] = cmul(x[t1], cur); cur = cmul(cur, r); }
  }
  __syncthreads();
  #pragma unroll
  for (int t1 = 0; t1 < 16; ++t1) tile[cc][t1*16 + ((j + t1) & 15)] = x[t1];
  __syncthreads();
  #pragma unroll
  for (int a2 = 0; a2 < 16; ++a2) x[a2] = tile[cc][j*16 + ((a2 + j) & 15)];
  dft16<DIR>(x);
  __syncthreads();  // before reusing tile as staging
  #pragma unroll
  for (int t2 = 0; t2 < 16; ++t2) tile[cc][j + 16*t2] = x[t2];
  __syncthreads();
  int ck2 = t & 15, rg2 = t >> 4;
  if (MODE == 0) {
    cplx* dst = outZ + (long)seq * NFFT + K0 + ck2;
    #pragma unroll
    for (int i = 0; i < 16; ++i) {
      int k2 = i*16 + rg2;
      dst[256*k2] = tile[ck2][k2];
    }
  } else {
    const float sc = 1.0f / 65536.0f;
    int gseq = seqBase + seq;
    float bf = bias[gseq & 15];
    float* dst = outR + (long)gseq * OUTW;
    #pragma unroll
    for (int i = 0; i < 16; ++i) {
      int k2 = i*16 + rg2;
      int s  = K0 + ck2 + 256*k2;
      int tp = 2*s;
      cplx v = tile[ck2][k2];
      if (tp < OUTW)     dst[tp]   = v.x * sc + bf;
      if (tp + 1 < OUTW) dst[tp+1] = v.y * sc + bf;
    }
  }
}

// Direct weight rfft: Y[seq][k] = sum_{t<128} w[seq][t] e^{-2 pi i k t / 131072}.
// Restructured as sum_v r^v * (sum_u w[8u+v] (r^8)^u): inner chains share one
// rotation update -> ~2.5 VALU instr/tap instead of 6.
__global__ __launch_bounds__(256)
void weight_spec(const float* __restrict__ wgt, cplx* __restrict__ Y) {
  int seq = blockIdx.y;
  int k = blockIdx.x * 256 + threadIdx.x;
  __shared__ float wt[128];
  if (threadIdx.x < 128) wt[threadIdx.x] = wgt[seq * 128 + threadIdx.x];
  __syncthreads();
  if (k > KEEPK) return;
  float sn, cs;
  __sincosf(-3.14159265358979324f * (float)k * (1.0f/65536.0f), &sn, &cs);
  cplx r  = cmk(cs, sn);
  cplx r2 = cmul(r, r);
  cplx r4 = cmul(r2, r2);
  cplx r8 = cmul(r4, r4);
  cplx av[8];
  #pragma unroll
  for (int v = 0; v < 8; ++v) av[v] = cmk(0.f, 0.f);
  cplx C = cmk(1.f, 0.f);
  #pragma unroll
  for (int u = 0; u < 16; ++u) {
    #pragma unroll
    for (int v = 0; v < 8; ++v) {
      float w = wt[u*8 + v];
      av[v].x += w * C.x;
      av[v].y += w * C.y;
    }
    C = cmul(C, r8);
  }
  // Horner combine: acc = av[0] + r*(av[1] + r*(... + r*av[7]))
  cplx acc = av[7];
  #pragma unroll
  for (int v = 6; v >= 0; --v) acc = cadd(av[v], cmul(r, acc));
  Y[(long)seq * 32769 + k] = acc;
}

// Fused: unpack X on the fly, 8-channel complex MAC vs conj(Y) for all 16 f,
// Hermitian-pack the masked product spectrum into inverse-FFT input Z.
// k-tile = 32 (LDS 32 KiB -> 5 blocks/CU), 8 n-groups per block.
__global__ __launch_bounds__(256)
void mac_pack(const cplx* __restrict__ Zx, const cplx* __restrict__ Yspec,
              cplx* __restrict__ Zout, int Bn) {
  int K0 = blockIdx.x * 32;
  int tid = threadIdx.x;
  int kk = tid & 31;
  int ng = tid >> 5;       // 8 thread-groups over n
  int k = K0 + kk;
  __shared__ cplx Yt[16][8][32];  // 32 KiB
  for (int e = tid; e < 16*8*32; e += 256) {
    int f = e >> 8;
    int c = (e >> 5) & 7;
    int q = e & 31;
    int kg = K0 + q;
    Yt[f][c][q] = (kg <= KEEPK) ? Yspec[(long)(f*8 + c) * 32769 + kg] : cmk(0.f, 0.f);
  }
  __syncthreads();
  if (k > KEEPK) return;
  float sn, cs;
  __sincosf(-3.14159265358979324f * (float)k * (1.0f/65536.0f), &sn, &cs);
  cplx w  = cmk(cs, sn);    // e^{-i pi k / 65536}
  cplx wp = cmk(cs, -sn);   // conj(w)
  int nPerG = (Bn + 7) >> 3;
  for (int nn = 0; nn < nPerG; ++nn) {
    int ln = ng * nPerG + nn;
    if (ln >= Bn) break;
    cplx X[8];
    #pragma unroll
    for (int c = 0; c < 8; ++c) {
      const cplx* Z = Zx + (long)(ln*8 + c) * NFFT;
      cplx zk = Z[k];
      cplx zm = Z[(NFFT - k) & (NFFT - 1)];
      cplx E = cmk(0.5f*(zk.x + zm.x), 0.5f*(zk.y - zm.y));
      cplx D = cmk(zk.x - zm.x, zk.y + zm.y);
      cplx O = cmk(0.5f*D.y, -0.5f*D.x);
      X[c] = cadd(E, cmul(w, O));
    }
    #pragma unroll
    for (int f = 0; f < 16; ++f) {
      cplx S = cmk(0.f, 0.f);
      #pragma unroll
      for (int c = 0; c < 8; ++c) S = cadd(S, cmulj(X[c], Yt[f][c][kk]));
      cplx* Zo = Zout + (long)(ln*16 + f) * NFFT;
      if (k == KEEPK) {
        Zo[k] = cmk(S.x, -S.y);                  // Z[M/2] = conj(S)
      } else {
        cplx E2 = cmk(0.5f*S.x, 0.5f*S.y);
        cplx O2 = cmul(wp, E2);                  // e^{+i pi k/M} * S/2
        Zo[k] = cmk(E2.x - O2.y, E2.y + O2.x);   // E + i O
        if (k > 0)
          Zo[NFFT - k] = cmk(E2.x + O2.y, O2.x - E2.y); // conj(E) + i conj(O)
      }
    }
  }
}

} // namespace

extern "C" void kernel_launch(void* const* d_in, const int* in_sizes, int n_in,
                              void* d_out, int out_size, void* d_ws, size_t ws_size,
                              hipStream_t stream) {
  const cplx*  x    = (const cplx*)d_in[0];   // (32,8,65536) f32 = 32768 cplx/seq, 256 seqs
  const float* wgt  = (const float*)d_in[1];  // (16,8,128)  f32, 128 seqs of 128 taps
  const float* bias = (const float*)d_in[2];  // (16,)
  float* out = (float*)d_out;                 // (32,16,65409) f32

  // Region plan: Y (33.6 MB) + Zx (Bn*8 seqs) + Zout (Bn*16) + T (Bn*16), batched over n.
  static const int BnOpt[5] = {16, 8, 4, 2, 1};
  int ti = 4;
  for (int i = 0; i < 5; ++i) {
    size_t zxb = (size_t)BnOpt[i] * 8  * NFFT * sizeof(cplx);
    size_t zob = (size_t)BnOpt[i] * 16 * NFFT * sizeof(cplx);
    if (YBYTES + zxb + 2 * zob <= ws_size) { ti = i; break; }
  }
  const int Bn = BnOpt[ti];
  const size_t zxb = (size_t)Bn * 8  * NFFT * sizeof(cplx);
  const size_t zob = (size_t)Bn * 16 * NFFT * sizeof(cplx);

  char* ws = (char*)d_ws;
  cplx* Y  = (cplx*)ws;                         // weight rfft spectrum, whole pipeline
  cplx* Zx = (cplx*)(ws + YBYTES);              // per-batch x spectra
  cplx* Zo = (cplx*)(ws + YBYTES + zxb);        // per-batch product spectra
  cplx* T  = (cplx*)(ws + YBYTES + zxb + zob);  // shared four-step temp

  // weight spectrum: one direct-DFT kernel
  weight_spec<<<dim3(129, 128), dim3(256), 0, stream>>>(wgt, Y);

  // per n-batch: x FFT -> MAC -> inverse FFT
  for (int n0 = 0; n0 < 32; n0 += Bn) {
    int sx = Bn * 8;   // x seqs this batch
    int so = Bn * 16;  // out seqs this batch
    fft_pass_a<-1><<<dim3(sx*16), dim3(256), 0, stream>>>(x + (long)n0*8*32768, 32768, 32768, T);
    fft_pass_b<-1,0><<<dim3(sx*16), dim3(256), 0, stream>>>(T, Zx, (float*)nullptr, (const float*)nullptr, 0);
    mac_pack<<<dim3(1025), dim3(256), 0, stream>>>(Zx, Y, Zo, Bn);
    fft_pass_a<1><<<dim3(so*16), dim3(256), 0, stream>>>(Zo, 65536, 65536, T);
    fft_pass_b<1,1><<<dim3(so*16), dim3(256), 0, stream>>>(T, (cplx*)nullptr, out, bias, n0*16);
  }
}